// Round 1
// baseline (431.610 us; speedup 1.0000x reference)
//
#include <hip/hip_runtime.h>
#include <math.h>

// Problem constants
#define Bsz 2
#define Hdim 64
#define Wdim 64
#define Cc 256
#define NHh 8
#define KWIN 7
#define HDd 32
#define NTOK (Bsz * Hdim * Wdim)  // 8192

// ---------------- LayerNorm: one block (256 threads) per token ----------------
__global__ __launch_bounds__(256) void ln_kernel(const float* __restrict__ x,
                                                 const float* __restrict__ w,
                                                 const float* __restrict__ b,
                                                 float* __restrict__ y) {
    int t = blockIdx.x;
    int c = threadIdx.x;
    float v = x[(size_t)t * Cc + c];
    float s = v, sq = v * v;
#pragma unroll
    for (int off = 32; off > 0; off >>= 1) {
        s  += __shfl_xor(s, off, 64);
        sq += __shfl_xor(sq, off, 64);
    }
    __shared__ float sh[8];
    int wave = threadIdx.x >> 6, lane = threadIdx.x & 63;
    if (lane == 0) { sh[wave] = s; sh[4 + wave] = sq; }
    __syncthreads();
    float sum = sh[0] + sh[1] + sh[2] + sh[3];
    float ssq = sh[4] + sh[5] + sh[6] + sh[7];
    float mean = sum * (1.0f / Cc);
    float var  = ssq * (1.0f / Cc) - mean * mean;
    float r = rsqrtf(var + 1e-5f);
    y[(size_t)t * Cc + c] = (v - mean) * r * w[c] + b[c];
}

// ---------------- fp32 GEMM: C[M,N] = A[M,K] @ W[N,K]^T + bias (+res / +gelu) --
// 64x64 tile, BK=16, 256 threads, 4x4 per thread.
// EPI: 0 = bias only, 1 = bias + residual, 2 = bias + exact GELU
template <int EPI>
__global__ __launch_bounds__(256) void gemm_kernel(const float* __restrict__ A,
                                                   const float* __restrict__ Wt,
                                                   const float* __restrict__ bias,
                                                   const float* __restrict__ res,
                                                   float* __restrict__ C,
                                                   int M, int N, int Kd) {
    __shared__ float As[16][68];  // [k][m], row stride 68 floats (272B, 16B-aligned)
    __shared__ float Bs[16][68];  // [k][n]
    const int tid = threadIdx.x;
    const int m0 = blockIdx.y * 64;
    const int n0 = blockIdx.x * 64;
    const int r  = tid >> 2;          // 0..63 tile row for loading
    const int c4 = (tid & 3) * 4;     // 0,4,8,12 k-offset for loading
    const int tm = (tid >> 4) * 4;    // 0..60 micro-tile row
    const int tn = (tid & 15) * 4;    // 0..60 micro-tile col

    float acc[4][4] = {};

    for (int kt = 0; kt < Kd; kt += 16) {
        float4 a  = *reinterpret_cast<const float4*>(&A [(size_t)(m0 + r) * Kd + kt + c4]);
        float4 wv = *reinterpret_cast<const float4*>(&Wt[(size_t)(n0 + r) * Kd + kt + c4]);
        As[c4 + 0][r] = a.x;  As[c4 + 1][r] = a.y;  As[c4 + 2][r] = a.z;  As[c4 + 3][r] = a.w;
        Bs[c4 + 0][r] = wv.x; Bs[c4 + 1][r] = wv.y; Bs[c4 + 2][r] = wv.z; Bs[c4 + 3][r] = wv.w;
        __syncthreads();
#pragma unroll
        for (int k = 0; k < 16; ++k) {
            float4 av = *reinterpret_cast<const float4*>(&As[k][tm]);
            float4 bv = *reinterpret_cast<const float4*>(&Bs[k][tn]);
            float aa[4] = {av.x, av.y, av.z, av.w};
            float bb[4] = {bv.x, bv.y, bv.z, bv.w};
#pragma unroll
            for (int i = 0; i < 4; ++i)
#pragma unroll
                for (int j = 0; j < 4; ++j) acc[i][j] += aa[i] * bb[j];
        }
        __syncthreads();
    }

#pragma unroll
    for (int i = 0; i < 4; ++i) {
        int row = m0 + tm + i;
        float ob[4];
#pragma unroll
        for (int j = 0; j < 4; ++j) {
            float v = acc[i][j] + bias[n0 + tn + j];
            if (EPI == 1) v += res[(size_t)row * N + n0 + tn + j];
            if (EPI == 2) v = 0.5f * v * (1.0f + erff(v * 0.70710678118654752f));
            ob[j] = v;
        }
        *reinterpret_cast<float4*>(&C[(size_t)row * N + n0 + tn]) =
            make_float4(ob[0], ob[1], ob[2], ob[3]);
    }
}

// ---------------- Neighborhood attention: one wave per (token, head) ----------
// qkv layout: [token, 768] with ch = t*256 + head*32 + d, t in {q=0,k=1,v=2}
// out layout: [token, 256] with ch = head*32 + d
__global__ __launch_bounds__(256) void natten_kernel(const float* __restrict__ qkv,
                                                     float* __restrict__ out) {
    __shared__ float sh_q[4][32];
    __shared__ float sh_p[4][52];
    const int wave = threadIdx.x >> 6;
    const int lane = threadIdx.x & 63;
    const int gid  = blockIdx.x * 4 + wave;   // 0..65535
    const int head  = gid & 7;
    const int token = gid >> 3;
    const int j  = token & 63;
    const int i  = (token >> 6) & 63;
    const int bb = token >> 12;
    int si = i - 3; si = si < 0 ? 0 : (si > Hdim - KWIN ? Hdim - KWIN : si);
    int sj = j - 3; sj = sj < 0 ? 0 : (sj > Wdim - KWIN ? Wdim - KWIN : sj);

    const float scale = 0.17677669529663687f;  // 1/sqrt(32)
    const float* qrow = qkv + (size_t)token * 768 + head * 32;
    if (lane < 32) sh_q[wave][lane] = qrow[lane] * scale;
    __syncthreads();

    // QK: lane = neighbor (49 active)
    float s = -INFINITY;
    if (lane < 49) {
        int di = lane / 7, dj = lane % 7;
        int nt = (bb * Hdim + si + di) * Wdim + (sj + dj);
        const float4* k4 = reinterpret_cast<const float4*>(qkv + (size_t)nt * 768 + 256 + head * 32);
        float accq = 0.f;
#pragma unroll
        for (int d4 = 0; d4 < 8; ++d4) {
            float4 kv = k4[d4];
            accq += sh_q[wave][d4 * 4 + 0] * kv.x + sh_q[wave][d4 * 4 + 1] * kv.y +
                    sh_q[wave][d4 * 4 + 2] * kv.z + sh_q[wave][d4 * 4 + 3] * kv.w;
        }
        s = accq;
    }
    // softmax over 49 (wave reduce across 64 lanes)
    float m = s;
#pragma unroll
    for (int off = 32; off > 0; off >>= 1) m = fmaxf(m, __shfl_xor(m, off, 64));
    float e = (lane < 49) ? __expf(s - m) : 0.f;
    float tot = e;
#pragma unroll
    for (int off = 32; off > 0; off >>= 1) tot += __shfl_xor(tot, off, 64);
    if (lane < 49) sh_p[wave][lane] = e / tot;
    __syncthreads();

    // AV: lane = d (32 active), coalesced v loads
    if (lane < 32) {
        float acc = 0.f;
        for (int kk = 0; kk < 49; ++kk) {
            int di = kk / 7, dj = kk % 7;
            int nt = (bb * Hdim + si + di) * Wdim + (sj + dj);
            acc += sh_p[wave][kk] * qkv[(size_t)nt * 768 + 512 + head * 32 + lane];
        }
        out[(size_t)token * 256 + head * 32 + lane] = acc;
    }
}

extern "C" void kernel_launch(void* const* d_in, const int* in_sizes, int n_in,
                              void* d_out, int out_size, void* d_ws, size_t ws_size,
                              hipStream_t stream) {
    const float* x      = (const float*)d_in[0];
    const float* ln1_w  = (const float*)d_in[1];
    const float* ln1_b  = (const float*)d_in[2];
    const float* qkv_w  = (const float*)d_in[3];
    const float* qkv_b  = (const float*)d_in[4];
    const float* proj_w = (const float*)d_in[5];
    const float* proj_b = (const float*)d_in[6];
    const float* ln2_w  = (const float*)d_in[7];
    const float* ln2_b  = (const float*)d_in[8];
    const float* fc1_w  = (const float*)d_in[9];
    const float* fc1_b  = (const float*)d_in[10];
    const float* fc2_w  = (const float*)d_in[11];
    const float* fc2_b  = (const float*)d_in[12];
    float* out = (float*)d_out;

    char* ws = (char*)d_ws;
    float* xn  = (float*)(ws);                                          // 8192*256
    float* qkv = (float*)(ws + (size_t)8192 * 256 * 4);                 // 8192*768
    float* x2  = (float*)(ws + (size_t)8192 * (256 + 768) * 4);         // 8192*256
    float* h1  = (float*)(ws + (size_t)8192 * (256 + 768 + 256) * 4);   // 8192*1024
    float* attn_out = xn;  // reuse (xn consumed by QKV gemm)
    float* h        = xn;  // reuse (attn_out consumed by proj gemm)

    dim3 blk(256);
    // 1. LN1
    ln_kernel<<<NTOK, blk, 0, stream>>>(x, ln1_w, ln1_b, xn);
    // 2. QKV = xn @ qkv_w^T + qkv_b   [8192 x 768], K=256
    gemm_kernel<0><<<dim3(768 / 64, 8192 / 64), blk, 0, stream>>>(xn, qkv_w, qkv_b, nullptr, qkv, 8192, 768, 256);
    // 3. Neighborhood attention
    natten_kernel<<<NTOK * NHh / 4, blk, 0, stream>>>(qkv, attn_out);
    // 4. x2 = x + attn_out @ proj_w^T + proj_b  [8192 x 256], K=256
    gemm_kernel<1><<<dim3(256 / 64, 8192 / 64), blk, 0, stream>>>(attn_out, proj_w, proj_b, x, x2, 8192, 256, 256);
    // 5. LN2
    ln_kernel<<<NTOK, blk, 0, stream>>>(x2, ln2_w, ln2_b, h);
    // 6. h1 = gelu(h @ fc1_w^T + fc1_b)  [8192 x 1024], K=256
    gemm_kernel<2><<<dim3(1024 / 64, 8192 / 64), blk, 0, stream>>>(h, fc1_w, fc1_b, nullptr, h1, 8192, 1024, 256);
    // 7. out = x2 + h1 @ fc2_w^T + fc2_b  [8192 x 256], K=1024
    gemm_kernel<1><<<dim3(256 / 64, 8192 / 64), blk, 0, stream>>>(h1, fc2_w, fc2_b, x2, out, 8192, 256, 1024);
}

// Round 2
// 191.950 us; speedup vs baseline: 2.2486x; 2.2486x over previous
//
#include <hip/hip_runtime.h>
#include <math.h>

#define Hdim 64
#define Wdim 64
#define Cc 256
#define NHh 8
#define NTOK 8192

typedef unsigned short ushortT;
typedef __attribute__((ext_vector_type(8))) short short8;
typedef __attribute__((ext_vector_type(4))) float floatx4;

__device__ inline ushortT f2bf(float x) {
    union { float f; unsigned u; } v; v.f = x;
    unsigned r = (v.u + 0x7fffu + ((v.u >> 16) & 1u)) >> 16;
    return (ushortT)r;
}

#define GLOAD_LDS16(g, l) __builtin_amdgcn_global_load_lds( \
    (const __attribute__((address_space(1))) unsigned int*)(g), \
    (__attribute__((address_space(3))) unsigned int*)(l), 16, 0, 0)

// ---------------- weight fp32 -> bf16 conversion (once per launch) -----------
__global__ __launch_bounds__(256) void convert_weights(
        const float* __restrict__ qkv_w, const float* __restrict__ proj_w,
        const float* __restrict__ fc1_w, const float* __restrict__ fc2_w,
        ushortT* __restrict__ o_qkv, ushortT* __restrict__ o_proj,
        ushortT* __restrict__ o_fc1, ushortT* __restrict__ o_fc2) {
    int idx = blockIdx.x * 256 + threadIdx.x;  // one float4 per thread
    const float* src; ushortT* dst; int local;
    if (idx < 49152)        { src = qkv_w;  dst = o_qkv;  local = idx; }
    else if (idx < 65536)   { src = proj_w; dst = o_proj; local = idx - 49152; }
    else if (idx < 131072)  { src = fc1_w;  dst = o_fc1;  local = idx - 65536; }
    else                    { src = fc2_w;  dst = o_fc2;  local = idx - 131072; }
    float4 v = ((const float4*)src)[local];
    ushortT o[4] = {f2bf(v.x), f2bf(v.y), f2bf(v.z), f2bf(v.w)};
    *(uint2*)(dst + (size_t)local * 4) = *(uint2*)o;
}

// ---------------- LayerNorm (fp32 in, bf16 out): one block per token ---------
__global__ __launch_bounds__(256) void ln_bf16(const float* __restrict__ x,
                                               const float* __restrict__ w,
                                               const float* __restrict__ b,
                                               ushortT* __restrict__ y) {
    int t = blockIdx.x;
    int c = threadIdx.x;
    float v = x[(size_t)t * Cc + c];
    float s = v, sq = v * v;
#pragma unroll
    for (int off = 32; off > 0; off >>= 1) {
        s  += __shfl_xor(s, off, 64);
        sq += __shfl_xor(sq, off, 64);
    }
    __shared__ float sh[8];
    int wave = threadIdx.x >> 6, lane = threadIdx.x & 63;
    if (lane == 0) { sh[wave] = s; sh[4 + wave] = sq; }
    __syncthreads();
    float sum = sh[0] + sh[1] + sh[2] + sh[3];
    float ssq = sh[4] + sh[5] + sh[6] + sh[7];
    float mean = sum * (1.0f / Cc);
    float var  = ssq * (1.0f / Cc) - mean * mean;
    float r = rsqrtf(var + 1e-5f);
    y[(size_t)t * Cc + c] = f2bf((v - mean) * r * w[c] + b[c]);
}

// ---------------- bf16 MFMA GEMM: C[M,N] = A[M,K] @ Bw[N,K]^T + bias ---------
// 128x128 tile, BK=32, 256 threads (4 waves 2x2), 16x16x32 MFMA, 4x4 tiles/wave
// EPI: 0 = bias, 1 = bias + fp32 residual, 2 = bias + exact GELU
template <int EPI, bool OUTBF>
__global__ __launch_bounds__(256) void gemm_bf16(const ushortT* __restrict__ A,
                                                 const ushortT* __restrict__ Bw,
                                                 const float* __restrict__ bias,
                                                 const float* __restrict__ res,
                                                 void* __restrict__ Cout,
                                                 int N, int K) {
    __shared__ ushortT As[128 * 32];  // [row][k] 64B rows
    __shared__ ushortT Bs[128 * 32];  // [n][k]
    const int tid  = threadIdx.x;
    const int wave = tid >> 6, lane = tid & 63;
    const int wm = wave >> 1, wn = wave & 1;
    const int ln16 = lane & 15, kg = lane >> 4;
    const int m0 = blockIdx.y * 128, n0 = blockIdx.x * 128;
    const int lrow = lane >> 2;        // row within 16-row chunk
    const int lcol = (lane & 3) * 8;   // k-element offset (16B)

    const floatx4 fzero = {0.f, 0.f, 0.f, 0.f};
    floatx4 acc[4][4];
#pragma unroll
    for (int i = 0; i < 4; ++i)
#pragma unroll
        for (int j = 0; j < 4; ++j) acc[i][j] = fzero;

    for (int kt = 0; kt < K; kt += 32) {
#pragma unroll
        for (int cc = 0; cc < 2; ++cc) {
            int ch = wave * 2 + cc;           // chunk 0..7 (1KB each)
            int row = ch * 16 + lrow;
            GLOAD_LDS16(A  + (size_t)(m0 + row) * K + kt + lcol, As + ch * 512);
            GLOAD_LDS16(Bw + (size_t)(n0 + row) * K + kt + lcol, Bs + ch * 512);
        }
        __syncthreads();
        short8 a[4], b[4];
#pragma unroll
        for (int i = 0; i < 4; ++i)
            a[i] = *(const short8*)(As + (wm * 64 + i * 16 + ln16) * 32 + kg * 8);
#pragma unroll
        for (int j = 0; j < 4; ++j)
            b[j] = *(const short8*)(Bs + (wn * 64 + j * 16 + ln16) * 32 + kg * 8);
#pragma unroll
        for (int i = 0; i < 4; ++i)
#pragma unroll
            for (int j = 0; j < 4; ++j)
                acc[i][j] = __builtin_amdgcn_mfma_f32_16x16x32_bf16(a[i], b[j], acc[i][j], 0, 0, 0);
        __syncthreads();
    }

    // epilogue: C/D map col=lane&15, row=(lane>>4)*4+reg
#pragma unroll
    for (int i = 0; i < 4; ++i) {
#pragma unroll
        for (int r = 0; r < 4; ++r) {
            int row = m0 + wm * 64 + i * 16 + kg * 4 + r;
#pragma unroll
            for (int j = 0; j < 4; ++j) {
                int col = n0 + wn * 64 + j * 16 + ln16;
                float v = acc[i][j][r] + bias[col];
                if (EPI == 1) v += res[(size_t)row * N + col];
                if (EPI == 2) v = 0.5f * v * (1.0f + erff(v * 0.70710678118654752f));
                if (OUTBF) ((ushortT*)Cout)[(size_t)row * N + col] = f2bf(v);
                else       ((float*)Cout)[(size_t)row * N + col]  = v;
            }
        }
    }
}

// ---------------- Neighborhood attention v2 ----------------------------------
// One block per (batch, head, 8x8 token tile). K union-tile (14x14) in LDS.
// 4 lanes per token; all 256 lanes active in QK, softmax, AV.
// qkv fp32 [token][768] (q|k|v each 256 = head*32+d); out bf16 [token][256].
__global__ __launch_bounds__(256) void natten_v2(const float* __restrict__ qkv,
                                                 ushortT* __restrict__ attn_out) {
    __shared__ float Ks[196][36];  // 14x14 window x 32 dims, stride 36 (16B-aligned rows)
    __shared__ float Ps[64][50];   // probs per token
    const int tid = threadIdx.x;
    const int bid = blockIdx.x;
    const int tile = bid & 63;
    const int h = (bid >> 6) & 7;
    const int b = bid >> 9;
    const int ti = tile >> 3, tj = tile & 7;
    const int r0 = min(max(ti * 8 - 3, 0), Hdim - 14);
    const int c0 = min(max(tj * 8 - 3, 0), Wdim - 14);

    // stage K union tile
    for (int idx = tid; idx < 196 * 8; idx += 256) {
        int pos = idx >> 3, q4 = idx & 7;
        int dr = pos / 14, dc = pos % 14;
        size_t tok = (size_t)((b * Hdim + r0 + dr) * Wdim + (c0 + dc));
        *(float4*)&Ks[pos][q4 * 4] = *(const float4*)(qkv + tok * 768 + 256 + h * 32 + q4 * 4);
    }
    __syncthreads();

    const int tl = tid >> 2, s = tid & 3;          // token-local, quarter
    const int i = ti * 8 + (tl >> 3), j = tj * 8 + (tl & 7);
    const int si = min(max(i - 3, 0), Hdim - 7), sj = min(max(j - 3, 0), Wdim - 7);
    const int lr = si - r0, lc = sj - c0;
    const size_t tq = (size_t)((b * Hdim + i) * Wdim + j);

    float q[32];
    {
        const float4* qp = (const float4*)(qkv + tq * 768 + h * 32);
#pragma unroll
        for (int d4 = 0; d4 < 8; ++d4) {
            float4 qv = qp[d4];
            q[d4 * 4 + 0] = qv.x * 0.17677669529663687f;
            q[d4 * 4 + 1] = qv.y * 0.17677669529663687f;
            q[d4 * 4 + 2] = qv.z * 0.17677669529663687f;
            q[d4 * 4 + 3] = qv.w * 0.17677669529663687f;
        }
    }

    // QK: neighbors n = s, s+4, ... (13 for s=0 else 12)
    float sc[13];
    int cnt = 0;
    for (int n = s; n < 49; n += 4) {
        int di = n / 7, dj = n - di * 7;
        const float* kr = &Ks[(lr + di) * 14 + (lc + dj)][0];
        float a = 0.f;
#pragma unroll
        for (int d4 = 0; d4 < 8; ++d4) {
            float4 kv = *(const float4*)(kr + d4 * 4);
            a += q[d4*4+0]*kv.x + q[d4*4+1]*kv.y + q[d4*4+2]*kv.z + q[d4*4+3]*kv.w;
        }
        sc[cnt++] = a;
    }
    // softmax across the 4-lane group
    float m = -1e30f;
    for (int c = 0; c < cnt; ++c) m = fmaxf(m, sc[c]);
    m = fmaxf(m, __shfl_xor(m, 1, 64));
    m = fmaxf(m, __shfl_xor(m, 2, 64));
    float tot = 0.f;
    for (int c = 0; c < cnt; ++c) { sc[c] = __expf(sc[c] - m); tot += sc[c]; }
    tot += __shfl_xor(tot, 1, 64);
    tot += __shfl_xor(tot, 2, 64);
    float inv = 1.0f / tot;
    cnt = 0;
    for (int n = s; n < 49; n += 4) Ps[tl][n] = sc[cnt++] * inv;
    __syncthreads();

    // AV: thread (tl, g=s) accumulates dims g*8..g*8+7; V straight from global (L1/L2)
    float o[8];
#pragma unroll
    for (int d = 0; d < 8; ++d) o[d] = 0.f;
    for (int di = 0; di < 7; ++di) {
        int row = si + di;
#pragma unroll
        for (int dj = 0; dj < 7; ++dj) {
            float p = Ps[tl][di * 7 + dj];
            size_t tokv = (size_t)((b * Hdim + row) * Wdim + (sj + dj));
            const float4* vp = (const float4*)(qkv + tokv * 768 + 512 + h * 32 + s * 8);
            float4 v0 = vp[0], v1 = vp[1];
            o[0] += p * v0.x; o[1] += p * v0.y; o[2] += p * v0.z; o[3] += p * v0.w;
            o[4] += p * v1.x; o[5] += p * v1.y; o[6] += p * v1.z; o[7] += p * v1.w;
        }
    }
    unsigned u[4];
#pragma unroll
    for (int d = 0; d < 4; ++d)
        u[d] = (unsigned)f2bf(o[2 * d]) | ((unsigned)f2bf(o[2 * d + 1]) << 16);
    *(uint4*)(attn_out + tq * 256 + h * 32 + s * 8) = make_uint4(u[0], u[1], u[2], u[3]);
}

extern "C" void kernel_launch(void* const* d_in, const int* in_sizes, int n_in,
                              void* d_out, int out_size, void* d_ws, size_t ws_size,
                              hipStream_t stream) {
    const float* x      = (const float*)d_in[0];
    const float* ln1_w  = (const float*)d_in[1];
    const float* ln1_b  = (const float*)d_in[2];
    const float* qkv_w  = (const float*)d_in[3];
    const float* qkv_b  = (const float*)d_in[4];
    const float* proj_w = (const float*)d_in[5];
    const float* proj_b = (const float*)d_in[6];
    const float* ln2_w  = (const float*)d_in[7];
    const float* ln2_b  = (const float*)d_in[8];
    const float* fc1_w  = (const float*)d_in[9];
    const float* fc1_b  = (const float*)d_in[10];
    const float* fc2_w  = (const float*)d_in[11];
    const float* fc2_b  = (const float*)d_in[12];
    float* out = (float*)d_out;

    char* ws = (char*)d_ws;
    size_t off = 0;
    ushortT* wqkv = (ushortT*)(ws + off); off += (size_t)196608 * 2;
    ushortT* wproj= (ushortT*)(ws + off); off += (size_t)65536 * 2;
    ushortT* wfc1 = (ushortT*)(ws + off); off += (size_t)262144 * 2;
    ushortT* wfc2 = (ushortT*)(ws + off); off += (size_t)262144 * 2;
    ushortT* xn   = (ushortT*)(ws + off); off += (size_t)NTOK * 256 * 2;
    float*   qkvb = (float*)  (ws + off); off += (size_t)NTOK * 768 * 4;
    ushortT* attn = (ushortT*)(ws + off); off += (size_t)NTOK * 256 * 2;
    float*   x2   = (float*)  (ws + off); off += (size_t)NTOK * 256 * 4;
    ushortT* hb   = (ushortT*)(ws + off); off += (size_t)NTOK * 256 * 2;
    ushortT* h1   = (ushortT*)(ws + off); off += (size_t)NTOK * 1024 * 2;

    dim3 blk(256);
    convert_weights<<<768, blk, 0, stream>>>(qkv_w, proj_w, fc1_w, fc2_w,
                                             wqkv, wproj, wfc1, wfc2);
    ln_bf16<<<NTOK, blk, 0, stream>>>(x, ln1_w, ln1_b, xn);
    gemm_bf16<0, false><<<dim3(6, 64), blk, 0, stream>>>(xn, wqkv, qkv_b, nullptr, qkvb, 768, 256);
    natten_v2<<<1024, blk, 0, stream>>>(qkvb, attn);
    gemm_bf16<1, false><<<dim3(2, 64), blk, 0, stream>>>(attn, wproj, proj_b, x, x2, 256, 256);
    ln_bf16<<<NTOK, blk, 0, stream>>>(x2, ln2_w, ln2_b, hb);
    gemm_bf16<2, true><<<dim3(8, 64), blk, 0, stream>>>(hb, wfc1, fc1_b, nullptr, h1, 1024, 256);
    gemm_bf16<1, false><<<dim3(2, 64), blk, 0, stream>>>(h1, wfc2, fc2_b, x2, out, 256, 1024);
}

// Round 3
// 169.347 us; speedup vs baseline: 2.5487x; 1.1335x over previous
//
#include <hip/hip_runtime.h>
#include <math.h>

#define Hdim 64
#define Wdim 64
#define Cc 256
#define NHh 8
#define NTOK 8192

typedef unsigned short ushortT;
typedef __attribute__((ext_vector_type(8))) short short8;
typedef __attribute__((ext_vector_type(4))) float floatx4;

__device__ inline ushortT f2bf(float x) {
    union { float f; unsigned u; } v; v.f = x;
    unsigned r = (v.u + 0x7fffu + ((v.u >> 16) & 1u)) >> 16;
    return (ushortT)r;
}

#define GLOAD_LDS16(g, l) __builtin_amdgcn_global_load_lds( \
    (const __attribute__((address_space(1))) unsigned int*)(g), \
    (__attribute__((address_space(3))) unsigned int*)(l), 16, 0, 0)

// ---------------- weight fp32 -> bf16 conversion (once per launch) -----------
__global__ __launch_bounds__(256) void convert_weights(
        const float* __restrict__ qkv_w, const float* __restrict__ proj_w,
        const float* __restrict__ fc1_w, const float* __restrict__ fc2_w,
        ushortT* __restrict__ o_qkv, ushortT* __restrict__ o_proj,
        ushortT* __restrict__ o_fc1, ushortT* __restrict__ o_fc2) {
    int idx = blockIdx.x * 256 + threadIdx.x;  // one float4 per thread
    const float* src; ushortT* dst; int local;
    if (idx < 49152)        { src = qkv_w;  dst = o_qkv;  local = idx; }
    else if (idx < 65536)   { src = proj_w; dst = o_proj; local = idx - 49152; }
    else if (idx < 131072)  { src = fc1_w;  dst = o_fc1;  local = idx - 65536; }
    else                    { src = fc2_w;  dst = o_fc2;  local = idx - 131072; }
    float4 v = ((const float4*)src)[local];
    ushortT o[4] = {f2bf(v.x), f2bf(v.y), f2bf(v.z), f2bf(v.w)};
    *(uint2*)(dst + (size_t)local * 4) = *(uint2*)o;
}

// ---------------- LayerNorm (fp32 in, bf16 out): one block per token ---------
__global__ __launch_bounds__(256) void ln_bf16(const float* __restrict__ x,
                                               const float* __restrict__ w,
                                               const float* __restrict__ b,
                                               ushortT* __restrict__ y) {
    int t = blockIdx.x;
    int c = threadIdx.x;
    float v = x[(size_t)t * Cc + c];
    float s = v, sq = v * v;
#pragma unroll
    for (int off = 32; off > 0; off >>= 1) {
        s  += __shfl_xor(s, off, 64);
        sq += __shfl_xor(sq, off, 64);
    }
    __shared__ float sh[8];
    int wave = threadIdx.x >> 6, lane = threadIdx.x & 63;
    if (lane == 0) { sh[wave] = s; sh[4 + wave] = sq; }
    __syncthreads();
    float sum = sh[0] + sh[1] + sh[2] + sh[3];
    float ssq = sh[4] + sh[5] + sh[6] + sh[7];
    float mean = sum * (1.0f / Cc);
    float var  = ssq * (1.0f / Cc) - mean * mean;
    float r = rsqrtf(var + 1e-5f);
    y[(size_t)t * Cc + c] = f2bf((v - mean) * r * w[c] + b[c]);
}

// ---------------- bf16 MFMA GEMM v2: C[M,N] = A[M,K] @ Bw[N,K]^T + bias ------
// 64x64 block tile, BK=64, 256 threads = 4 waves (2x2), each wave 32x32.
// LDS: [row][128B], XOR-swizzled chunks: global chunk g of row r at pos g^(r&7).
// Staged via global_load_lds width-16 (wave-uniform base + lane*16).
// EPI: 0 = bias, 1 = bias + fp32 residual, 2 = bias + exact GELU
template <int EPI, bool OUTBF>
__global__ __launch_bounds__(256) void gemm_bf16_v2(const ushortT* __restrict__ A,
                                                    const ushortT* __restrict__ Bw,
                                                    const float* __restrict__ bias,
                                                    const float* __restrict__ res,
                                                    void* __restrict__ Cout,
                                                    int N, int K) {
    __shared__ ushortT As[64 * 64];  // 64 rows x 64 ushorts (128B), 8KB
    __shared__ ushortT Bs[64 * 64];
    const int tid  = threadIdx.x;
    const int wave = tid >> 6, lane = tid & 63;
    const int wm = wave >> 1, wn = wave & 1;
    const int ln16 = lane & 15, kg = lane >> 4;
    const int m0 = blockIdx.y * 64, n0 = blockIdx.x * 64;
    // staging: global 16B-chunk index (swizzled), in ushort units
    const int g8 = (((lane & 7) ^ (lane >> 3)) * 8);
    const int srow = wave * 16 + (lane >> 3);  // +8 for pass 1

    const floatx4 fzero = {0.f, 0.f, 0.f, 0.f};
    floatx4 acc[2][2];
#pragma unroll
    for (int i = 0; i < 2; ++i)
#pragma unroll
        for (int j = 0; j < 2; ++j) acc[i][j] = fzero;

    for (int kt = 0; kt < K; kt += 64) {
#pragma unroll
        for (int p = 0; p < 2; ++p) {
            int row = srow + p * 8;
            GLOAD_LDS16(A  + (size_t)(m0 + row) * K + kt + g8, As + wave * 1024 + p * 512);
            GLOAD_LDS16(Bw + (size_t)(n0 + row) * K + kt + g8, Bs + wave * 1024 + p * 512);
        }
        __syncthreads();
#pragma unroll
        for (int s = 0; s < 2; ++s) {
            short8 a[2], b[2];
#pragma unroll
            for (int i = 0; i < 2; ++i) {
                int ra = wm * 32 + i * 16 + ln16;
                a[i] = *(const short8*)(As + ra * 64 + (((s * 4 + kg) ^ (ln16 & 7)) * 8));
            }
#pragma unroll
            for (int j = 0; j < 2; ++j) {
                int rb = wn * 32 + j * 16 + ln16;
                b[j] = *(const short8*)(Bs + rb * 64 + (((s * 4 + kg) ^ (ln16 & 7)) * 8));
            }
#pragma unroll
            for (int i = 0; i < 2; ++i)
#pragma unroll
                for (int j = 0; j < 2; ++j)
                    acc[i][j] = __builtin_amdgcn_mfma_f32_16x16x32_bf16(a[i], b[j], acc[i][j], 0, 0, 0);
        }
        __syncthreads();
    }

    // epilogue: C/D map col=lane&15, row=(lane>>4)*4+reg
#pragma unroll
    for (int i = 0; i < 2; ++i) {
#pragma unroll
        for (int r = 0; r < 4; ++r) {
            int row = m0 + wm * 32 + i * 16 + kg * 4 + r;
#pragma unroll
            for (int j = 0; j < 2; ++j) {
                int col = n0 + wn * 32 + j * 16 + ln16;
                float v = acc[i][j][r] + bias[col];
                if (EPI == 1) v += res[(size_t)row * N + col];
                if (EPI == 2) v = 0.5f * v * (1.0f + erff(v * 0.70710678118654752f));
                if (OUTBF) ((ushortT*)Cout)[(size_t)row * N + col] = f2bf(v);
                else       ((float*)Cout)[(size_t)row * N + col]  = v;
            }
        }
    }
}

// ---------------- Neighborhood attention v2 ----------------------------------
// One block per (batch, head, 8x8 token tile). K union-tile (14x14) in LDS.
// 4 lanes per token; all 256 lanes active in QK, softmax, AV.
// qkv fp32 [token][768] (q|k|v each 256 = head*32+d); out bf16 [token][256].
__global__ __launch_bounds__(256) void natten_v2(const float* __restrict__ qkv,
                                                 ushortT* __restrict__ attn_out) {
    __shared__ float Ks[196][36];  // 14x14 window x 32 dims, stride 36 (16B-aligned rows)
    __shared__ float Ps[64][50];   // probs per token
    const int tid = threadIdx.x;
    const int bid = blockIdx.x;
    const int tile = bid & 63;
    const int h = (bid >> 6) & 7;
    const int b = bid >> 9;
    const int ti = tile >> 3, tj = tile & 7;
    const int r0 = min(max(ti * 8 - 3, 0), Hdim - 14);
    const int c0 = min(max(tj * 8 - 3, 0), Wdim - 14);

    // stage K union tile
    for (int idx = tid; idx < 196 * 8; idx += 256) {
        int pos = idx >> 3, q4 = idx & 7;
        int dr = pos / 14, dc = pos % 14;
        size_t tok = (size_t)((b * Hdim + r0 + dr) * Wdim + (c0 + dc));
        *(float4*)&Ks[pos][q4 * 4] = *(const float4*)(qkv + tok * 768 + 256 + h * 32 + q4 * 4);
    }
    __syncthreads();

    const int tl = tid >> 2, s = tid & 3;          // token-local, quarter
    const int i = ti * 8 + (tl >> 3), j = tj * 8 + (tl & 7);
    const int si = min(max(i - 3, 0), Hdim - 7), sj = min(max(j - 3, 0), Wdim - 7);
    const int lr = si - r0, lc = sj - c0;
    const size_t tq = (size_t)((b * Hdim + i) * Wdim + j);

    float q[32];
    {
        const float4* qp = (const float4*)(qkv + tq * 768 + h * 32);
#pragma unroll
        for (int d4 = 0; d4 < 8; ++d4) {
            float4 qv = qp[d4];
            q[d4 * 4 + 0] = qv.x * 0.17677669529663687f;
            q[d4 * 4 + 1] = qv.y * 0.17677669529663687f;
            q[d4 * 4 + 2] = qv.z * 0.17677669529663687f;
            q[d4 * 4 + 3] = qv.w * 0.17677669529663687f;
        }
    }

    // QK: neighbors n = s, s+4, ... (13 for s=0 else 12)
    float sc[13];
    int cnt = 0;
    for (int n = s; n < 49; n += 4) {
        int di = n / 7, dj = n - di * 7;
        const float* kr = &Ks[(lr + di) * 14 + (lc + dj)][0];
        float a = 0.f;
#pragma unroll
        for (int d4 = 0; d4 < 8; ++d4) {
            float4 kv = *(const float4*)(kr + d4 * 4);
            a += q[d4*4+0]*kv.x + q[d4*4+1]*kv.y + q[d4*4+2]*kv.z + q[d4*4+3]*kv.w;
        }
        sc[cnt++] = a;
    }
    // softmax across the 4-lane group
    float m = -1e30f;
    for (int c = 0; c < cnt; ++c) m = fmaxf(m, sc[c]);
    m = fmaxf(m, __shfl_xor(m, 1, 64));
    m = fmaxf(m, __shfl_xor(m, 2, 64));
    float tot = 0.f;
    for (int c = 0; c < cnt; ++c) { sc[c] = __expf(sc[c] - m); tot += sc[c]; }
    tot += __shfl_xor(tot, 1, 64);
    tot += __shfl_xor(tot, 2, 64);
    float inv = 1.0f / tot;
    cnt = 0;
    for (int n = s; n < 49; n += 4) Ps[tl][n] = sc[cnt++] * inv;
    __syncthreads();

    // AV: thread (tl, g=s) accumulates dims g*8..g*8+7; V straight from global (L1/L2)
    float o[8];
#pragma unroll
    for (int d = 0; d < 8; ++d) o[d] = 0.f;
    for (int di = 0; di < 7; ++di) {
        int row = si + di;
#pragma unroll
        for (int dj = 0; dj < 7; ++dj) {
            float p = Ps[tl][di * 7 + dj];
            size_t tokv = (size_t)((b * Hdim + row) * Wdim + (sj + dj));
            const float4* vp = (const float4*)(qkv + tokv * 768 + 512 + h * 32 + s * 8);
            float4 v0 = vp[0], v1 = vp[1];
            o[0] += p * v0.x; o[1] += p * v0.y; o[2] += p * v0.z; o[3] += p * v0.w;
            o[4] += p * v1.x; o[5] += p * v1.y; o[6] += p * v1.z; o[7] += p * v1.w;
        }
    }
    unsigned u[4];
#pragma unroll
    for (int d = 0; d < 4; ++d)
        u[d] = (unsigned)f2bf(o[2 * d]) | ((unsigned)f2bf(o[2 * d + 1]) << 16);
    *(uint4*)(attn_out + tq * 256 + h * 32 + s * 8) = make_uint4(u[0], u[1], u[2], u[3]);
}

extern "C" void kernel_launch(void* const* d_in, const int* in_sizes, int n_in,
                              void* d_out, int out_size, void* d_ws, size_t ws_size,
                              hipStream_t stream) {
    const float* x      = (const float*)d_in[0];
    const float* ln1_w  = (const float*)d_in[1];
    const float* ln1_b  = (const float*)d_in[2];
    const float* qkv_w  = (const float*)d_in[3];
    const float* qkv_b  = (const float*)d_in[4];
    const float* proj_w = (const float*)d_in[5];
    const float* proj_b = (const float*)d_in[6];
    const float* ln2_w  = (const float*)d_in[7];
    const float* ln2_b  = (const float*)d_in[8];
    const float* fc1_w  = (const float*)d_in[9];
    const float* fc1_b  = (const float*)d_in[10];
    const float* fc2_w  = (const float*)d_in[11];
    const float* fc2_b  = (const float*)d_in[12];
    float* out = (float*)d_out;

    char* ws = (char*)d_ws;
    size_t off = 0;
    ushortT* wqkv = (ushortT*)(ws + off); off += (size_t)196608 * 2;
    ushortT* wproj= (ushortT*)(ws + off); off += (size_t)65536 * 2;
    ushortT* wfc1 = (ushortT*)(ws + off); off += (size_t)262144 * 2;
    ushortT* wfc2 = (ushortT*)(ws + off); off += (size_t)262144 * 2;
    ushortT* xn   = (ushortT*)(ws + off); off += (size_t)NTOK * 256 * 2;
    float*   qkvb = (float*)  (ws + off); off += (size_t)NTOK * 768 * 4;
    ushortT* attn = (ushortT*)(ws + off); off += (size_t)NTOK * 256 * 2;
    float*   x2   = (float*)  (ws + off); off += (size_t)NTOK * 256 * 4;
    ushortT* hb   = (ushortT*)(ws + off); off += (size_t)NTOK * 256 * 2;
    ushortT* h1   = (ushortT*)(ws + off); off += (size_t)NTOK * 1024 * 2;

    dim3 blk(256);
    convert_weights<<<768, blk, 0, stream>>>(qkv_w, proj_w, fc1_w, fc2_w,
                                             wqkv, wproj, wfc1, wfc2);
    ln_bf16<<<NTOK, blk, 0, stream>>>(x, ln1_w, ln1_b, xn);
    gemm_bf16_v2<0, false><<<dim3(12, 128), blk, 0, stream>>>(xn, wqkv, qkv_b, nullptr, qkvb, 768, 256);
    natten_v2<<<1024, blk, 0, stream>>>(qkvb, attn);
    gemm_bf16_v2<1, false><<<dim3(4, 128), blk, 0, stream>>>(attn, wproj, proj_b, x, x2, 256, 256);
    ln_bf16<<<NTOK, blk, 0, stream>>>(x2, ln2_w, ln2_b, hb);
    gemm_bf16_v2<2, true><<<dim3(16, 128), blk, 0, stream>>>(hb, wfc1, fc1_b, nullptr, h1, 1024, 256);
    gemm_bf16_v2<1, false><<<dim3(4, 128), blk, 0, stream>>>(h1, wfc2, fc2_b, x2, out, 256, 1024);
}